// Round 3
// baseline (63.297 us; speedup 1.0000x reference)
//
#include <hip/hip_runtime.h>

// Holt-Winters, producer/consumer tiled.
// 256 blocks x 256 threads; block owns 32 rows.
//   wave 0  : compute. lane r (<32) owns row row0+r. State (L, c=L+b) +
//             seasonal buf[24] in registers; 96-step tile bodies statically
//             unrolled (96 % 24 == 0 -> compile-time phases, rule #20 safe).
//   waves1-3: loaders. Stage x-tiles into LDS with coalesced float4 loads,
//             drain out-tiles with coalesced float4 stores (full 64B lines ->
//             no write amplification). Double-buffered both directions,
//             one __syncthreads per 96-step tile.

#define RPB 32      // rows per block
#define WT  96      // tile width (floats), multiple of 24
#define STR 100     // LDS row stride (16B-aligned, 4-way b128 conflict only)
#define NG  24      // WT/4 float4 groups per tile

__global__ __launch_bounds__(256, 1) void hw_tiled_kernel(
    const float* __restrict__ temp,
    const float* __restrict__ alpha,
    const float* __restrict__ beta,
    const float* __restrict__ gamma,
    const float* __restrict__ L0,
    const float* __restrict__ b0,
    const float* __restrict__ S0,
    float* __restrict__ out,
    int N, int T)
{
    __shared__ float xt[2][RPB * STR];
    __shared__ float ot[2][RPB * STR];

    const int tid  = threadIdx.x;
    const int wave = tid >> 6;
    const int row0 = blockIdx.x * RPB;
    const int ntiles = (T + WT - 1) / WT;

    // loader mapping (waves 1..3): q in [0,192), 6 lanes per row
    const int q    = tid - 64;
    const int lr   = (q < 0 ? 0 : q) / 6;
    const int lj   = (q < 0 ? 0 : q) - lr * 6;
    const int lrow = row0 + lr;

    float buf[24];
    float L = 0.f, c = 0.f;
    float a_ = 0.f, bt = 0.f, g_ = 0.f, oma = 0.f, omb = 0.f, opb = 0.f, omg = 0.f;
    const bool act = (wave == 0) && (tid < RPB) && (row0 + tid < N);

    if (wave == 0) {
        a_  = alpha[0]; bt = beta[0]; g_ = gamma[0];
        oma = 1.0f - a_; omb = 1.0f - bt; opb = 1.0f + bt; omg = 1.0f - g_;
        #pragma unroll
        for (int k = 0; k < 24; ++k) buf[k] = 0.f;
        if (act) {
            const float* s0r = S0 + (size_t)(row0 + tid) * 24;
            #pragma unroll
            for (int k = 0; k < 24; ++k) buf[k] = s0r[k];
            L = L0[row0 + tid];
            c = L + b0[row0 + tid];
        }
    } else if (lrow < N) {
        // prologue: stage x tile 0 into buffer 0
        const float* xr = temp + (size_t)lrow * T;
        #pragma unroll
        for (int m = 0; m < 4; ++m) {
            const int f = 4 * (lj + 6 * m);
            if (f + 4 <= T) {
                *reinterpret_cast<float4*>(&xt[0][lr * STR + f]) =
                    *reinterpret_cast<const float4*>(xr + f);
            } else {
                #pragma unroll
                for (int e = 0; e < 4; ++e)
                    if (f + e < T) xt[0][lr * STR + f + e] = xr[f + e];
            }
        }
    }
    __syncthreads();

    for (int i = 0; i < ntiles; ++i) {
        if (wave == 0) {
            if (act) {
                const int tb = i * WT;
                const float* xb = &xt[i & 1][tid * STR];
                float*       ob = &ot[i & 1][tid * STR];
                float4 xq[6];
                #pragma unroll
                for (int p = 0; p < 6; ++p)
                    xq[p] = *reinterpret_cast<const float4*>(&xb[4 * p]);
                float og[4] = {0.f, 0.f, 0.f, 0.f};

#define COMPX(K) ( ((K)&3)==0 ? xq[((K)/4)%6].x : \
                   ((K)&3)==1 ? xq[((K)/4)%6].y : \
                   ((K)&3)==2 ? xq[((K)/4)%6].z : xq[((K)/4)%6].w )

#define STEP_RAW(K) { \
    const float x  = COMPX(K); \
    const float s  = buf[(K)%24]; \
    const float Ln = fmaf(oma, c, a_ * (x - s)); \
    const float t1 = fmaf(omb, c, -L); \
    const float cn = fmaf(opb, Ln, t1); \
    const float sn = fmaf(g_, x - Ln, omg * s); \
    buf[(K)%24] = sn; \
    og[(K)&3] = cn * sn; \
    L = Ln; c = cn; }

#define GSTEP(K) { \
    const int tt = tb + (K); \
    if (tt == 0) { og[0] = c * buf[0]; } \
    else if (tt < T) STEP_RAW(K) }

#define DOGROUP(G) { \
    const int t4 = tb + 4 * (G); \
    if (t4 >= 1 && t4 + 4 <= T) { \
        STEP_RAW(4*(G)+0) STEP_RAW(4*(G)+1) STEP_RAW(4*(G)+2) STEP_RAW(4*(G)+3) \
    } else { \
        GSTEP(4*(G)+0) GSTEP(4*(G)+1) GSTEP(4*(G)+2) GSTEP(4*(G)+3) \
    } \
    *reinterpret_cast<float4*>(&ob[4*(G)]) = \
        make_float4(og[0], og[1], og[2], og[3]); \
    if ((G) + 6 < NG) \
        xq[(G)%6] = *reinterpret_cast<const float4*>(&xb[4*((G)+6)]); }

                DOGROUP(0)  DOGROUP(1)  DOGROUP(2)  DOGROUP(3)
                DOGROUP(4)  DOGROUP(5)  DOGROUP(6)  DOGROUP(7)
                DOGROUP(8)  DOGROUP(9)  DOGROUP(10) DOGROUP(11)
                DOGROUP(12) DOGROUP(13) DOGROUP(14) DOGROUP(15)
                DOGROUP(16) DOGROUP(17) DOGROUP(18) DOGROUP(19)
                DOGROUP(20) DOGROUP(21) DOGROUP(22) DOGROUP(23)

#undef DOGROUP
#undef GSTEP
#undef STEP_RAW
#undef COMPX
            }
        } else if (lrow < N) {
            // stage next x tile
            if (i + 1 < ntiles) {
                const int tb = (i + 1) * WT;
                const int b  = (i + 1) & 1;
                const float* xr = temp + (size_t)lrow * T;
                #pragma unroll
                for (int m = 0; m < 4; ++m) {
                    const int f = 4 * (lj + 6 * m);
                    if (tb + f + 4 <= T) {
                        *reinterpret_cast<float4*>(&xt[b][lr * STR + f]) =
                            *reinterpret_cast<const float4*>(xr + tb + f);
                    } else {
                        #pragma unroll
                        for (int e = 0; e < 4; ++e)
                            if (tb + f + e < T) xt[b][lr*STR+f+e] = xr[tb+f+e];
                    }
                }
            }
            // drain previous out tile
            if (i >= 1) {
                const int tb = (i - 1) * WT;
                const int b  = (i - 1) & 1;
                float* orw = out + (size_t)lrow * T;
                #pragma unroll
                for (int m = 0; m < 4; ++m) {
                    const int f = 4 * (lj + 6 * m);
                    if (tb + f + 4 <= T) {
                        *reinterpret_cast<float4*>(orw + tb + f) =
                            *reinterpret_cast<const float4*>(&ot[b][lr * STR + f]);
                    } else {
                        #pragma unroll
                        for (int e = 0; e < 4; ++e)
                            if (tb + f + e < T) orw[tb+f+e] = ot[b][lr*STR+f+e];
                    }
                }
            }
        }
        __syncthreads();
    }

    // epilogue: drain the final out tile
    if (wave != 0 && lrow < N) {
        const int i  = ntiles - 1;
        const int tb = i * WT;
        const int b  = i & 1;
        float* orw = out + (size_t)lrow * T;
        #pragma unroll
        for (int m = 0; m < 4; ++m) {
            const int f = 4 * (lj + 6 * m);
            if (tb + f + 4 <= T) {
                *reinterpret_cast<float4*>(orw + tb + f) =
                    *reinterpret_cast<const float4*>(&ot[b][lr * STR + f]);
            } else {
                #pragma unroll
                for (int e = 0; e < 4; ++e)
                    if (tb + f + e < T) orw[tb+f+e] = ot[b][lr*STR+f+e];
            }
        }
    }
}

extern "C" void kernel_launch(void* const* d_in, const int* in_sizes, int n_in,
                              void* d_out, int out_size, void* d_ws, size_t ws_size,
                              hipStream_t stream) {
    const float* temp  = (const float*)d_in[0];
    const float* alpha = (const float*)d_in[1];
    const float* beta  = (const float*)d_in[2];
    const float* gamma = (const float*)d_in[3];
    const float* L0    = (const float*)d_in[4];
    const float* b0    = (const float*)d_in[5];
    const float* S0    = (const float*)d_in[6];
    float* out = (float*)d_out;

    const int N = in_sizes[4];          // L0 length
    const int T = in_sizes[0] / N;      // temp is (N, T)

    const int grid = (N + RPB - 1) / RPB;   // 256 blocks -> all 256 CUs
    hw_tiled_kernel<<<grid, 256, 0, stream>>>(
        temp, alpha, beta, gamma, L0, b0, S0, out, N, T);
}